// Round 1
// baseline (629.862 us; speedup 1.0000x reference)
//
#include <hip/hip_runtime.h>

#define NGRAPH 4096
#define NNODE  64
#define NDIM   128
#define NLAYER 3

// W transposed per layer: g_wT[l][d][k] = W[l][k][d]; 192 KB device global
// (avoids depending on ws_size; rewritten every launch by transpose kernel).
__device__ float g_wT[NLAYER * NDIM * NDIM];

__global__ __launch_bounds__(256) void transpose_w_kernel(const float* __restrict__ W) {
  int idx = blockIdx.x * 256 + threadIdx.x;      // 0 .. 49151 (exact: 192 blocks)
  int l = idx / (NDIM * NDIM);
  int r = idx - l * NDIM * NDIM;
  int d = r >> 7;      // r / 128
  int k = r & 127;     // r % 128
  g_wT[idx] = W[l * NDIM * NDIM + k * NDIM + d];
}

__global__ __launch_bounds__(256, 2) void mpnn_kernel(
    const int* __restrict__ fps, const float* __restrict__ adj,
    const float* __restrict__ emb, const float* __restrict__ bias,
    float* __restrict__ out) {
  __shared__ float sh[NNODE * NDIM];   // 32 KB: h
  __shared__ float sz[NNODE * NDIM];   // 32 KB: z

  const int g  = blockIdx.x;
  const int t  = threadIdx.x;
  const int q  = t & 31;     // lane-within-32: spans k (or d) contiguously
  const int rt = t >> 5;     // 0..7: row group
  const int c0 = q << 2;     // column base (4 floats per thread)
  const int n0 = rt << 3;    // row base (8 rows per thread)

  // ---- gather: h[n][d] = emb[fps[n]][d] ----
  const int* fg = fps + g * NNODE;
  for (int i = 0; i < 8; ++i) {
    int n  = (i << 3) + rt;
    int fp = fg[n];
    float4 v = *(const float4*)(emb + fp * NDIM + c0);
    *(float4*)(sh + n * NDIM + c0) = v;
  }
  __syncthreads();

  const float* adjg = adj + (size_t)g * NNODE * NNODE;

  for (int l = 0; l < NLAYER; ++l) {
    // ---- linear: z[n][k] = relu(b[k] + sum_d h[n][d] * W[k][d]) via wT[d][k] ----
    const float* wTl = g_wT + l * NDIM * NDIM;
    float4 bv = *(const float4*)(bias + l * NDIM + c0);
    float acc[8][4];
#pragma unroll
    for (int i = 0; i < 8; ++i) {
      acc[i][0] = bv.x; acc[i][1] = bv.y; acc[i][2] = bv.z; acc[i][3] = bv.w;
    }
#pragma unroll 2
    for (int d4 = 0; d4 < NDIM; d4 += 4) {
      float4 w0 = *(const float4*)(wTl + (d4 + 0) * NDIM + c0);
      float4 w1 = *(const float4*)(wTl + (d4 + 1) * NDIM + c0);
      float4 w2 = *(const float4*)(wTl + (d4 + 2) * NDIM + c0);
      float4 w3 = *(const float4*)(wTl + (d4 + 3) * NDIM + c0);
#pragma unroll
      for (int i = 0; i < 8; ++i) {
        float4 hv = *(const float4*)(sh + (n0 + i) * NDIM + d4);  // broadcast read
        acc[i][0] += hv.x * w0.x + hv.y * w1.x + hv.z * w2.x + hv.w * w3.x;
        acc[i][1] += hv.x * w0.y + hv.y * w1.y + hv.z * w2.y + hv.w * w3.y;
        acc[i][2] += hv.x * w0.z + hv.y * w1.z + hv.z * w2.z + hv.w * w3.z;
        acc[i][3] += hv.x * w0.w + hv.y * w1.w + hv.z * w2.w + hv.w * w3.w;
      }
    }
#pragma unroll
    for (int i = 0; i < 8; ++i) {
      float4 zv;
      zv.x = fmaxf(acc[i][0], 0.f);
      zv.y = fmaxf(acc[i][1], 0.f);
      zv.z = fmaxf(acc[i][2], 0.f);
      zv.w = fmaxf(acc[i][3], 0.f);
      *(float4*)(sz + (n0 + i) * NDIM + c0) = zv;   // lane-consecutive: conflict-free
    }
    __syncthreads();

    // ---- message pass: h[m][d] = z[m][d] + sum_n adj[m][n] * z[n][d] ----
    float a2[8][4];
#pragma unroll
    for (int i = 0; i < 8; ++i) {
      float4 zv = *(const float4*)(sz + (n0 + i) * NDIM + c0);
      a2[i][0] = zv.x; a2[i][1] = zv.y; a2[i][2] = zv.z; a2[i][3] = zv.w;
    }
#pragma unroll 2
    for (int n4 = 0; n4 < NNODE; n4 += 4) {
      float4 z0 = *(const float4*)(sz + (n4 + 0) * NDIM + c0);
      float4 z1 = *(const float4*)(sz + (n4 + 1) * NDIM + c0);
      float4 z2 = *(const float4*)(sz + (n4 + 2) * NDIM + c0);
      float4 z3 = *(const float4*)(sz + (n4 + 3) * NDIM + c0);
#pragma unroll
      for (int i = 0; i < 8; ++i) {
        float4 av = *(const float4*)(adjg + (n0 + i) * NNODE + n4);  // broadcast, L2/L3
        a2[i][0] += av.x * z0.x + av.y * z1.x + av.z * z2.x + av.w * z3.x;
        a2[i][1] += av.x * z0.y + av.y * z1.y + av.z * z2.y + av.w * z3.y;
        a2[i][2] += av.x * z0.z + av.y * z1.z + av.z * z2.z + av.w * z3.z;
        a2[i][3] += av.x * z0.w + av.y * z1.w + av.z * z2.w + av.w * z3.w;
      }
    }
    // no barrier needed: adj phase reads only sz/adj, writes only sh
#pragma unroll
    for (int i = 0; i < 8; ++i) {
      float4 hv;
      hv.x = a2[i][0]; hv.y = a2[i][1]; hv.z = a2[i][2]; hv.w = a2[i][3];
      *(float4*)(sh + (n0 + i) * NDIM + c0) = hv;
    }
    __syncthreads();
  }

  // ---- sum pool: out[g][d] = sum_n h[n][d] ----
  if (t < NDIM) {
    float s = 0.f;
#pragma unroll 8
    for (int n = 0; n < NNODE; ++n) s += sh[n * NDIM + t];  // 2-way alias: free
    out[(size_t)g * NDIM + t] = s;
  }
}

extern "C" void kernel_launch(void* const* d_in, const int* in_sizes, int n_in,
                              void* d_out, int out_size, void* d_ws, size_t ws_size,
                              hipStream_t stream) {
  const int*   fps  = (const int*)d_in[0];
  const float* adj  = (const float*)d_in[1];
  const float* emb  = (const float*)d_in[2];
  const float* W    = (const float*)d_in[3];
  const float* bias = (const float*)d_in[4];
  float* out = (float*)d_out;

  hipLaunchKernelGGL(transpose_w_kernel, dim3(192), dim3(256), 0, stream, W);
  hipLaunchKernelGGL(mpnn_kernel, dim3(NGRAPH), dim3(256), 0, stream,
                     fps, adj, emb, bias, out);
}

// Round 2
// 281.584 us; speedup vs baseline: 2.2369x; 2.2369x over previous
//
#include <hip/hip_runtime.h>
#include <hip/hip_bf16.h>

#define NGRAPH 4096
#define NNODE  64
#define NDIM   128
#define NLAYER 3
#define PH  136   // h pitch in bf16 elems (128 + 8 pad, keeps 16B alignment, breaks bank stride)
#define PZT 72    // zT pitch (64 + 8 pad)
#define PA  136   // adj hi|lo pitch (128 + 8 pad)

typedef __attribute__((ext_vector_type(8))) short short8;
typedef __attribute__((ext_vector_type(4))) float f32x4;

// W in bf16, native [l][k_out][d] layout (torch Linear: z = h*W^T, so B[d][k_out]=W[k_out][d]
// and the MFMA B-fragment wants contiguous d per lane -> W's own row-major layout is perfect).
__device__ __align__(16) ushort g_wbf[NLAYER * NDIM * NDIM];

static __device__ inline ushort f2bf(float f) {  // RNE fp32 -> bf16
  unsigned int u = __float_as_uint(f);
  u += 0x7FFF + ((u >> 16) & 1);
  return (ushort)(u >> 16);
}
static __device__ inline float bf2f(ushort h) {
  return __uint_as_float((unsigned int)h << 16);
}

__global__ __launch_bounds__(256) void convert_w(const float* __restrict__ W) {
  int i = blockIdx.x * 256 + threadIdx.x;   // 192 blocks, exact
  g_wbf[i] = f2bf(W[i]);
}

__global__ __launch_bounds__(256, 3) void mpnn_mfma(
    const int* __restrict__ fps, const float* __restrict__ adj,
    const float* __restrict__ emb, const float* __restrict__ bias,
    float* __restrict__ out) {
  __shared__ __align__(16) ushort sh[NNODE * PH];     // h, bf16 row-major   (17408 B)
  __shared__ __align__(16) ushort szT[NDIM * PZT];    // z transposed, bf16  (18432 B)
  __shared__ __align__(16) ushort sadj[NNODE * PA];   // adj hi (cols 0..63) | lo (64..127) (17408 B)

  const int g    = blockIdx.x;
  const int t    = threadIdx.x;
  const int w    = t >> 6;       // wave 0..3
  const int lane = t & 63;
  const int r    = lane & 15;    // MFMA row/col-within-tile index
  const int q    = lane >> 4;    // quad 0..3
  const int m0   = w << 4;       // this wave's row slab [m0, m0+16)

  // ---- gather h0 = bf16(emb[fps]) ----
  const int* fg = fps + g * NNODE;
#pragma unroll
  for (int it = 0; it < 8; ++it) {
    int idx = it * 256 + t;              // 0..2047 float4s
    int n = idx >> 5;                    // 32 float4 per row
    int c = (idx & 31) << 2;
    float4 v = *(const float4*)(emb + fg[n] * NDIM + c);
    ushort4 u = {f2bf(v.x), f2bf(v.y), f2bf(v.z), f2bf(v.w)};
    *(ushort4*)(sh + n * PH + c) = u;
  }
  // ---- adj -> bf16 hi/lo split (makes A ~fp32-accurate at +64 MFMA/graph-layer) ----
  const float* adjg = adj + (size_t)g * NNODE * NNODE;
#pragma unroll
  for (int it = 0; it < 4; ++it) {
    int idx = it * 256 + t;              // 0..1023 float4s
    int n = idx >> 4;                    // 16 float4 per row
    int c = (idx & 15) << 2;
    float4 v = *(const float4*)(adjg + n * NNODE + c);
    ushort4 hi = {f2bf(v.x), f2bf(v.y), f2bf(v.z), f2bf(v.w)};
    ushort4 lo = {f2bf(v.x - bf2f(hi.x)), f2bf(v.y - bf2f(hi.y)),
                  f2bf(v.z - bf2f(hi.z)), f2bf(v.w - bf2f(hi.w))};
    *(ushort4*)(sadj + n * PA + c) = hi;
    *(ushort4*)(sadj + n * PA + 64 + c) = lo;
  }
  __syncthreads();

  for (int l = 0; l < NLAYER; ++l) {
    const ushort* Wl = g_wbf + l * NDIM * NDIM;
    const float*  bl = bias + l * NDIM;

    // ---- linear: acc[nt] = bias + h(slab) * W^T, MFMA 16x16x32 ----
    f32x4 acc[8];
#pragma unroll
    for (int nt = 0; nt < 8; ++nt) {
      float bv = bl[nt * 16 + r];        // C/D col = lane&15 -> bias is per-col, fp32
      acc[nt] = (f32x4){bv, bv, bv, bv};
    }
#pragma unroll
    for (int k0 = 0; k0 < NDIM; k0 += 32) {
      short8 av = *(const short8*)(sh + (m0 + r) * PH + k0 + 8 * q);   // A[m=r][k=8q+j]
#pragma unroll
      for (int nt = 0; nt < 8; ++nt) {
        short8 bv = *(const short8*)(Wl + (nt * 16 + r) * NDIM + k0 + 8 * q); // B[k][n=r]
        acc[nt] = __builtin_amdgcn_mfma_f32_16x16x32_bf16(av, bv, acc[nt], 0, 0, 0);
      }
    }
    // ---- relu; z kept fp32 in acc (residual C-init); bf16 z^T to LDS for B-operand ----
#pragma unroll
    for (int nt = 0; nt < 8; ++nt) {
      f32x4 z;
      z[0] = fmaxf(acc[nt][0], 0.f); z[1] = fmaxf(acc[nt][1], 0.f);
      z[2] = fmaxf(acc[nt][2], 0.f); z[3] = fmaxf(acc[nt][3], 0.f);
      acc[nt] = z;
      ushort4 u = {f2bf(z[0]), f2bf(z[1]), f2bf(z[2]), f2bf(z[3])};
      // C-frag rows m0+4q..+3 are consecutive -> one b64 write into z^T[col][row]
      *(ushort4*)(szT + (nt * 16 + r) * PZT + m0 + 4 * q) = u;
    }
    __syncthreads();

    // ---- h = z + A*z as K=128 matmul [A_hi|A_lo] * [zT;zT], C-init = fp32 z ----
    short8 a0 = *(const short8*)(sadj + (m0 + r) * PA +  0 + 8 * q);
    short8 a1 = *(const short8*)(sadj + (m0 + r) * PA + 32 + 8 * q);
    short8 a2 = *(const short8*)(sadj + (m0 + r) * PA + 64 + 8 * q);
    short8 a3 = *(const short8*)(sadj + (m0 + r) * PA + 96 + 8 * q);
#pragma unroll
    for (int nt = 0; nt < 8; ++nt) {
      short8 b0 = *(const short8*)(szT + (nt * 16 + r) * PZT +  0 + 8 * q);
      short8 b1 = *(const short8*)(szT + (nt * 16 + r) * PZT + 32 + 8 * q);
      acc[nt] = __builtin_amdgcn_mfma_f32_16x16x32_bf16(a0, b0, acc[nt], 0, 0, 0);
      acc[nt] = __builtin_amdgcn_mfma_f32_16x16x32_bf16(a1, b1, acc[nt], 0, 0, 0);
      acc[nt] = __builtin_amdgcn_mfma_f32_16x16x32_bf16(a2, b0, acc[nt], 0, 0, 0);
      acc[nt] = __builtin_amdgcn_mfma_f32_16x16x32_bf16(a3, b1, acc[nt], 0, 0, 0);
    }

    if (l < NLAYER - 1) {
      // scatter h (bf16) back row-major for next layer's A-frags (own slab only)
#pragma unroll
      for (int nt = 0; nt < 8; ++nt)
#pragma unroll
        for (int i = 0; i < 4; ++i)
          sh[(m0 + 4 * q + i) * PH + nt * 16 + r] = f2bf(acc[nt][i]);
      __syncthreads();   // protects szT from next layer's overwrite + h visibility
    } else {
      // ---- sum-pool: out[g][d] = sum_n h[n][d], fp32 throughout ----
      // pool aliases sh: after the mid-layer barrier no one reads sh again.
      float* pool = (float*)sh;          // [4 waves][128] floats = 2048 B
      float cs[8];
#pragma unroll
      for (int nt = 0; nt < 8; ++nt) {
        float s = acc[nt][0] + acc[nt][1] + acc[nt][2] + acc[nt][3];  // 4 rows in-lane
        s += __shfl_xor(s, 16, 64);      // sum over quads (rows within slab)
        s += __shfl_xor(s, 32, 64);
        cs[nt] = s;
      }
      if (q == 0) {
#pragma unroll
        for (int nt = 0; nt < 8; ++nt) pool[w * 128 + nt * 16 + r] = cs[nt];
      }
      __syncthreads();
      if (t < NDIM)
        out[(size_t)g * NDIM + t] = pool[t] + pool[128 + t] + pool[256 + t] + pool[384 + t];
    }
  }
}

extern "C" void kernel_launch(void* const* d_in, const int* in_sizes, int n_in,
                              void* d_out, int out_size, void* d_ws, size_t ws_size,
                              hipStream_t stream) {
  const int*   fps  = (const int*)d_in[0];
  const float* adj  = (const float*)d_in[1];
  const float* emb  = (const float*)d_in[2];
  const float* W    = (const float*)d_in[3];
  const float* bias = (const float*)d_in[4];
  float* out = (float*)d_out;

  hipLaunchKernelGGL(convert_w, dim3(192), dim3(256), 0, stream, W);
  hipLaunchKernelGGL(mpnn_mfma, dim3(NGRAPH), dim3(256), 0, stream,
                     fps, adj, emb, bias, out);
}

// Round 3
// 185.843 us; speedup vs baseline: 3.3892x; 1.5152x over previous
//
#include <hip/hip_runtime.h>

#define NGRAPH 4096
#define NNODE  64
#define NDIM   128
#define NLAYER 3
#define PH 152   // sh pitch (elems): stride 76 dwords === 12 mod 32 -> bank-balanced b128 row reads
#define PZ 88    // szT pitch (elems): stride 44 dwords === 12 mod 32

typedef __attribute__((ext_vector_type(8))) short short8;
typedef __attribute__((ext_vector_type(4))) float f32x4;

// W in bf16, native [l][k_out][d] layout: MFMA B-frag (lane r = col k_out, 8 consecutive d)
// reads W rows directly -> no transpose needed anywhere.
__device__ __align__(16) ushort g_wbf[NLAYER * NDIM * NDIM];

static __device__ inline ushort f2bf(float f) {  // RNE fp32 -> bf16
  unsigned int u = __float_as_uint(f);
  u += 0x7FFF + ((u >> 16) & 1);
  return (ushort)(u >> 16);
}
static __device__ inline float bf2f(ushort h) {
  return __uint_as_float((unsigned int)h << 16);
}

__global__ __launch_bounds__(256) void convert_w(const float* __restrict__ W) {
  int i = blockIdx.x * 256 + threadIdx.x;   // 192 blocks, exact
  g_wbf[i] = f2bf(W[i]);
}

__global__ __launch_bounds__(256, 3) void mpnn_mfma(
    const int* __restrict__ fps, const float* __restrict__ adj,
    const float* __restrict__ emb, const float* __restrict__ bias,
    float* __restrict__ out) {
  __shared__ __align__(16) ushort sh[NNODE * PH];   // h  bf16 [node][d]   19456 B
  __shared__ __align__(16) ushort szT[NDIM * PZ];   // zT bf16 [k|d][node] 22528 B

  const int g    = blockIdx.x;
  const int t    = threadIdx.x;
  const int w    = t >> 6;        // wave 0..3
  const int lane = t & 63;
  const int r    = lane & 15;     // MFMA row/col index
  const int q    = lane >> 4;     // quad 0..3
  const int n0   = w << 5;        // wave's 32-wide k_out slab (m1) == d slab (m2)

  // ---- gather h0 = bf16(emb[fps]) ----
  const int* fg = fps + g * NNODE;
#pragma unroll
  for (int it = 0; it < 8; ++it) {
    int idx = it * 256 + t;               // 2048 float4s
    int n = idx >> 5;
    int c = (idx & 31) << 2;
    float4 v = *(const float4*)(emb + fg[n] * NDIM + c);
    ushort4 u = {f2bf(v.x), f2bf(v.y), f2bf(v.z), f2bf(v.w)};
    *(ushort4*)(sh + n * PH + c) = u;
  }

  // ---- adjacency fragments -> registers (hi/lo split of A' = I + A) ----
  // fadj[nt][s]: B-frag for output-node tile nt; s = {0,1}: hi k=[0,32)/[32,64); {2,3}: lo.
  const float* adjg = adj + (size_t)g * NNODE * NNODE;
  short8 fadj[4][4];
  union S8 { short8 s8; ushort u[8]; };
#pragma unroll
  for (int nt = 0; nt < 4; ++nt) {
    int row = nt * 16 + r;                // output node (B-frag column)
    const float* rp = adjg + row * NNODE;
#pragma unroll
    for (int kh = 0; kh < 2; ++kh) {
      int cb = kh * 32 + 8 * q;           // k (source node) base
      float4 v0 = *(const float4*)(rp + cb);
      float4 v1 = *(const float4*)(rp + cb + 4);
      float vv[8] = {v0.x, v0.y, v0.z, v0.w, v1.x, v1.y, v1.z, v1.w};
      S8 hi, lo;
#pragma unroll
      for (int j = 0; j < 8; ++j) {
        float a = vv[j] + ((row == cb + j) ? 1.0f : 0.0f);   // fold residual: I + A
        ushort hb = f2bf(a);
        hi.u[j] = hb;
        lo.u[j] = f2bf(a - bf2f(hb));
      }
      fadj[nt][kh]     = hi.s8;
      fadj[nt][2 + kh] = lo.s8;
    }
  }
  __syncthreads();

  for (int l = 0; l < NLAYER; ++l) {
    const ushort* Wl = g_wbf + l * NDIM * NDIM;
    const float*  bl = bias + l * NDIM;

    // ---- m1: z[node][n0..n0+32) = relu(h * W^T + b)  (A = h rows, B = W rows) ----
    f32x4 acc[4][2];
#pragma unroll
    for (int nt = 0; nt < 2; ++nt) {
      float bv = bl[n0 + nt * 16 + r];
#pragma unroll
      for (int mt = 0; mt < 4; ++mt) acc[mt][nt] = (f32x4){bv, bv, bv, bv};
    }
#pragma unroll
    for (int k0 = 0; k0 < NDIM; k0 += 32) {
      short8 bw0 = *(const short8*)(Wl + (n0 + r) * NDIM + k0 + 8 * q);
      short8 bw1 = *(const short8*)(Wl + (n0 + 16 + r) * NDIM + k0 + 8 * q);
#pragma unroll
      for (int mt = 0; mt < 4; ++mt) {
        short8 ah = *(const short8*)(sh + (mt * 16 + r) * PH + k0 + 8 * q);
        acc[mt][0] = __builtin_amdgcn_mfma_f32_16x16x32_bf16(ah, bw0, acc[mt][0], 0, 0, 0);
        acc[mt][1] = __builtin_amdgcn_mfma_f32_16x16x32_bf16(ah, bw1, acc[mt][1], 0, 0, 0);
      }
    }
    // relu -> bf16 -> szT[k_out][node]  (C-frag: 4 consecutive nodes per lane -> b64)
#pragma unroll
    for (int mt = 0; mt < 4; ++mt)
#pragma unroll
      for (int nt = 0; nt < 2; ++nt) {
        ushort4 u = {f2bf(fmaxf(acc[mt][nt][0], 0.f)), f2bf(fmaxf(acc[mt][nt][1], 0.f)),
                     f2bf(fmaxf(acc[mt][nt][2], 0.f)), f2bf(fmaxf(acc[mt][nt][3], 0.f))};
        *(ushort4*)(szT + (n0 + nt * 16 + r) * PZ + mt * 16 + 4 * q) = u;
      }

    // ---- m2: houtT[d in n0-slab][node] = zT * (I+A)^T   (A = own szT rows, B = reg adj) ----
    f32x4 acc2[2][4];
#pragma unroll
    for (int mt = 0; mt < 2; ++mt)
#pragma unroll
      for (int nt = 0; nt < 4; ++nt) acc2[mt][nt] = (f32x4){0.f, 0.f, 0.f, 0.f};
#pragma unroll
    for (int kh = 0; kh < 2; ++kh) {
#pragma unroll
      for (int mt = 0; mt < 2; ++mt) {
        short8 az = *(const short8*)(szT + (n0 + mt * 16 + r) * PZ + kh * 32 + 8 * q);
#pragma unroll
        for (int nt = 0; nt < 4; ++nt) {
          acc2[mt][nt] = __builtin_amdgcn_mfma_f32_16x16x32_bf16(az, fadj[nt][kh], acc2[mt][nt], 0, 0, 0);
          acc2[mt][nt] = __builtin_amdgcn_mfma_f32_16x16x32_bf16(az, fadj[nt][2 + kh], acc2[mt][nt], 0, 0, 0);
        }
      }
    }

    if (l < NLAYER - 1) {
      __syncthreads();   // all waves done reading sh (m1 A-frags)
      // houtT C-frag: 4 consecutive d per lane, node col = nt*16+r -> b64 into sh[node][d]
#pragma unroll
      for (int mt = 0; mt < 2; ++mt)
#pragma unroll
        for (int nt = 0; nt < 4; ++nt) {
          ushort4 u = {f2bf(acc2[mt][nt][0]), f2bf(acc2[mt][nt][1]),
                       f2bf(acc2[mt][nt][2]), f2bf(acc2[mt][nt][3])};
          *(ushort4*)(sh + (nt * 16 + r) * PH + n0 + mt * 16 + 4 * q) = u;
        }
      __syncthreads();   // sh ready for next layer
    } else {
      // ---- sum-pool from C-frags: out[g][d] = sum_node houtT[d][node] ----
#pragma unroll
      for (int mt = 0; mt < 2; ++mt) {
        f32x4 s;
#pragma unroll
        for (int i = 0; i < 4; ++i)
          s[i] = acc2[mt][0][i] + acc2[mt][1][i] + acc2[mt][2][i] + acc2[mt][3][i];
#pragma unroll
        for (int m = 1; m <= 8; m <<= 1) {
          s[0] += __shfl_xor(s[0], m);
          s[1] += __shfl_xor(s[1], m);
          s[2] += __shfl_xor(s[2], m);
          s[3] += __shfl_xor(s[3], m);
        }
        if (r == 0) {
          float4 o = {s[0], s[1], s[2], s[3]};
          *(float4*)(out + (size_t)g * NDIM + n0 + mt * 16 + 4 * q) = o;
        }
      }
    }
  }
}

extern "C" void kernel_launch(void* const* d_in, const int* in_sizes, int n_in,
                              void* d_out, int out_size, void* d_ws, size_t ws_size,
                              hipStream_t stream) {
  const int*   fps  = (const int*)d_in[0];
  const float* adj  = (const float*)d_in[1];
  const float* emb  = (const float*)d_in[2];
  const float* W    = (const float*)d_in[3];
  const float* bias = (const float*)d_in[4];
  float* out = (float*)d_out;

  hipLaunchKernelGGL(convert_w, dim3(192), dim3(256), 0, stream, W);
  hipLaunchKernelGGL(mpnn_mfma, dim3(NGRAPH), dim3(256), 0, stream,
                     fps, adj, emb, bias, out);
}